// Round 5
// baseline (1498.994 us; speedup 1.0000x reference)
//
#include <hip/hip_runtime.h>

typedef float vf2 __attribute__((ext_vector_type(2)));
typedef float vf4 __attribute__((ext_vector_type(4)));

constexpr int N_PTS  = 1048576;
constexpr int D      = 32;
constexpr int Q      = 4;
constexpr int K      = 256;
constexpr int P      = 4;    // points per thread (residuals in VGPRs)
constexpr int BLOCK  = 256;
constexpr int STRIDE = 36;   // LDS row stride in floats: 16B-aligned, bank-skewed
#define TAU 4e-4f            // score-margin below which we replicate ref fp32 exactly

__device__ __forceinline__ vf2 mkv2(float a, float b) { vf2 t; t.x = a; t.y = b; return t; }

// XLA-style sequential FMA sum of squares: acc = fma(a[i],a[i],acc), i ascending.
__device__ __forceinline__ float seq_sumsq32(const float* a) {
#pragma clang fp contract(off)
    float acc = 0.0f;
    #pragma unroll
    for (int i = 0; i < 32; ++i) acc = __builtin_fmaf(a[i], a[i], acc);
    return acc;
}

__global__ __launch_bounds__(BLOCK)
void rvq_kernel(const float* __restrict__ x, const float* __restrict__ cb,
                float* __restrict__ out_xq, float* __restrict__ out_loss,
                float* __restrict__ out_idx)
{
#pragma clang fp contract(off)
    __shared__ float lds_cb[K * STRIDE];
    __shared__ float lds_c[K];   // ||e||^2, sequential-FMA order

    const int tid = threadIdx.x;
    const long long base_pt = ((long long)blockIdx.x * BLOCK + tid) * P;
    const float* xp = x + base_pt * D;

    // load P residuals (=x) into registers as float2 pairs (element order preserved)
    vf2 r[P][16];
    #pragma unroll
    for (int p = 0; p < P; ++p) {
        const vf4* src = (const vf4*)(xp + p * D);
        #pragma unroll
        for (int j = 0; j < 8; ++j) {
            vf4 v = src[j];
            r[p][2*j]   = mkv2(v.x, v.y);
            r[p][2*j+1] = mkv2(v.z, v.w);
        }
    }

    float loss_acc = 0.0f;
    float idx_out[P][Q];

    for (int q = 0; q < Q; ++q) {
        __syncthreads();  // protect LDS from previous stage's readers
        // stage codebook q into LDS (row per thread) + sequential-FMA ||e||^2
        {
            const float* cbq = cb + (size_t)q * K * D;
            const vf4* src = (const vf4*)(cbq + tid * D);
            vf4* dst = (vf4*)(lds_cb + tid * STRIDE);
            float e32[32];
            #pragma unroll
            for (int j = 0; j < 8; ++j) {
                vf4 v = src[j];
                dst[j] = v;
                e32[4*j] = v.x; e32[4*j+1] = v.y; e32[4*j+2] = v.z; e32[4*j+3] = v.w;
            }
            lds_c[tid] = seq_sumsq32(e32);
        }
        __syncthreads();

        float best[P], best2[P];
        int   bidx[P];
        #pragma unroll
        for (int p = 0; p < P; ++p) { best[p] = -1e30f; best2[p] = -1e30f; bidx[p] = 0; }

        // fast path: packed-fp32 scores (order differs from ref; rescue covers ties)
        #pragma unroll 2
        for (int k = 0; k < K; ++k) {
            vf2 e[16];
            const vf4* row = (const vf4*)(lds_cb + k * STRIDE);
            #pragma unroll
            for (int j = 0; j < 8; ++j) {
                vf4 v = row[j];
                e[2*j]   = mkv2(v.x, v.y);
                e[2*j+1] = mkv2(v.z, v.w);
            }
            float ck = lds_c[k];
            #pragma unroll
            for (int p = 0; p < P; ++p) {
                vf2 a0 = mkv2(0.f, 0.f), a1 = mkv2(0.f, 0.f);
                #pragma unroll
                for (int j = 0; j < 16; j += 2) {
                    a0 = __builtin_elementwise_fma(r[p][j],     e[j],     a0);
                    a1 = __builtin_elementwise_fma(r[p][j + 1], e[j + 1], a1);
                }
                float score = ((a0.x + a0.y) + (a1.x + a1.y)) - 0.5f * ck;
                bool gt = score > best[p];
                best2[p] = gt ? best[p] : fmaxf(best2[p], score);
                best[p]  = gt ? score : best[p];
                bidx[p]  = gt ? k : bidx[p];
            }
        }

        // near-tie rescue: replicate sequential-fp32 (XLA-style) d bitwise.
        // A = seqFMA(r*r); B_k = seqFMA dot; d_k = fl(fl(A - 2B_k) + C_k); first-min.
        #pragma unroll
        for (int p = 0; p < P; ++p) {
            if (best[p] - best2[p] < TAU) {
                const float* rr = (const float*)&r[p][0];  // 32 floats, element order
                float A = seq_sumsq32(rr);
                float bd = 1e30f; int bi = 0;
                for (int k = 0; k < K; k += 4) {
                    float d4[4];
                    #pragma unroll
                    for (int u = 0; u < 4; ++u) {
                        const float* row = lds_cb + (k + u) * STRIDE;
                        float acc = 0.0f;
                        #pragma unroll
                        for (int i = 0; i < D; ++i)
                            acc = __builtin_fmaf(rr[i], row[i], acc);
                        float t = A - 2.0f * acc;   // 2*acc exact; one rounding
                        d4[u] = t + lds_c[k + u];   // one rounding
                    }
                    #pragma unroll
                    for (int u = 0; u < 4; ++u) {
                        if (d4[u] < bd) { bd = d4[u]; bi = k + u; }  // strict <: first min
                    }
                }
                bidx[p] = bi;
            }
        }

        // carry update, replicating the reference's 3-step fp32 chain:
        // t = fl(xq - r); xq_st = fl(r + t); r' = fl(r - xq_st)
        #pragma unroll
        for (int p = 0; p < P; ++p) {
            const vf4* row = (const vf4*)(lds_cb + bidx[p] * STRIDE);
            #pragma unroll
            for (int j = 0; j < 8; ++j) {
                vf4 v = row[j];
                vf2 e0 = mkv2(v.x, v.y), e1 = mkv2(v.z, v.w);
                vf2 r0 = r[p][2*j], r1 = r[p][2*j+1];
                vf2 t0 = e0 - r0, t1 = e1 - r1;          // fl(xq - r)
                vf2 s0 = r0 + t0, s1 = r1 + t1;          // xq_st
                r[p][2*j]   = r0 - s0;                   // new residual
                r[p][2*j+1] = r1 - s1;
                loss_acc += t0.x * t0.x + t0.y * t0.y + t1.x * t1.x + t1.y * t1.y;
            }
            idx_out[p][q] = (float)bidx[p];
        }
    }

    // x_q = x - final residual (within ~1e-6 of ref's accumulated xq_st; thr 5.1)
    #pragma unroll
    for (int p = 0; p < P; ++p) {
        const vf4* src = (const vf4*)(xp + p * D);
        vf4* dst = (vf4*)(out_xq + (base_pt + p) * D);
        #pragma unroll
        for (int j = 0; j < 8; ++j) {
            vf4 v = src[j];
            vf2 o0 = mkv2(v.x, v.y) - r[p][2*j];
            vf2 o1 = mkv2(v.z, v.w) - r[p][2*j+1];
            vf4 o; o.x = o0.x; o.y = o0.y; o.z = o1.x; o.w = o1.y;
            dst[j] = o;
        }
    }

    // indices as float
    #pragma unroll
    for (int p = 0; p < P; ++p) {
        #pragma unroll
        for (int qq = 0; qq < Q; ++qq)
            out_idx[(base_pt + p) * Q + qq] = idx_out[p][qq];
    }

    // loss: wave64 shuffle reduce, one atomic per wave
    #pragma unroll
    for (int off = 32; off > 0; off >>= 1)
        loss_acc += __shfl_down(loss_acc, off, 64);
    if ((tid & 63) == 0) {
        const float scale = 1.25f / (float)((long long)Q * N_PTS * D);
        atomicAdd(out_loss, loss_acc * scale);
    }
}

extern "C" void kernel_launch(void* const* d_in, const int* in_sizes, int n_in,
                              void* d_out, int out_size, void* d_ws, size_t ws_size,
                              hipStream_t stream) {
    const float* x  = (const float*)d_in[0];
    const float* cb = (const float*)d_in[1];
    float* out      = (float*)d_out;
    float* out_xq   = out;                               // N*D
    float* out_loss = out + (size_t)N_PTS * D;           // 1
    float* out_idx  = out_loss + 1;                      // N*Q

    // harness poisons d_out with 0xAA before every timed launch
    hipMemsetAsync(out_loss, 0, sizeof(float), stream);

    dim3 grid(N_PTS / (BLOCK * P));
    dim3 block(BLOCK);
    rvq_kernel<<<grid, block, 0, stream>>>(x, cb, out_xq, out_loss, out_idx);
}